// Round 6
// baseline (609.906 us; speedup 1.0000x reference)
//
#include <hip/hip_runtime.h>

// ---------------- problem constants ----------------
constexpr int nB = 8, nS = 512, nH = 8, nD = 64, nHID = 512;
constexpr int THOP = 32, TEDGE = 16;
constexpr float SCALE = 0.125f;   // 64^-0.5
constexpr float NEGINF = -30000.0f;

typedef __attribute__((ext_vector_type(8))) short bf16x8;   // 8 bf16 = 4 VGPR
typedef __attribute__((ext_vector_type(4))) float f32x4;

#define MFMA16(A, B, C) __builtin_amdgcn_mfma_f32_16x16x32_bf16(A, B, C, 0, 0, 0)

// ---------------- module-scope scratch ----------------
__device__ __align__(16) unsigned short g_qhi[(size_t)nB * nH * nS * nD];  // [bh][s][d]
__device__ __align__(16) unsigned short g_qlo[(size_t)nB * nH * nS * nD];
__device__ __align__(16) unsigned short g_khi[(size_t)nB * nH * nS * nD];
__device__ __align__(16) unsigned short g_klo[(size_t)nB * nH * nS * nD];
__device__ __align__(16) unsigned short g_vhiT[(size_t)nB * nH * nD * nS]; // [bh][d][s]
__device__ __align__(16) unsigned short g_vloT[(size_t)nB * nH * nD * nS];
// hi/lo bf16 split of q/k hop+edge embeddings: qhe@0, khe@32*512, qee@64*512, kee@80*512
__device__ __align__(16) unsigned short g_embh[96 * 512];
__device__ __align__(16) unsigned short g_embl[96 * 512];
// pre-split GEMM inputs: q,k,v flattened [3][2M]
__device__ __align__(16) unsigned short g_inhi[(size_t)3 * 2097152];
__device__ __align__(16) unsigned short g_inlo[(size_t)3 * 2097152];
// pre-transposed+split weights W^T [mat][n][k], mats {Wq,Wk,Wv,Wo}
__device__ __align__(16) unsigned short g_wth[(size_t)4 * 262144];
__device__ __align__(16) unsigned short g_wtl[(size_t)4 * 262144];
// attn output, hi/lo bf16 [b*s][hid]
__device__ __align__(16) unsigned short g_xhi[(size_t)nB * nS * nHID];
__device__ __align__(16) unsigned short g_xlo[(size_t)nB * nS * nHID];
// 0:dist64 1:edge64 2:mmode 3:fmode ; dtype flags (0=bf16,1=fp32):
// 4..20 = q,k,v,qhe,qee,khe,kee,vhe,vee,Wq,bq,Wk,bk,Wv,bv,Wo,bo
__device__ int g_flags[32];

// adaptive scalar load: bf16 or fp32 element i
__device__ __forceinline__ float ldf(const void* p, int isf32, size_t i) {
  if (isf32) return ((const float*)p)[i];
  unsigned int w = (unsigned int)(((const unsigned short*)p)[i]) << 16;
  return __uint_as_float(w);
}
__device__ __forceinline__ float bf2f(unsigned short h) {
  return __uint_as_float((unsigned)h << 16);
}
__device__ __forceinline__ float4 ldf4(const void* p, int isf32, size_t i) {
  if (isf32) return ((const float4*)p)[i >> 2];
  const ushort4 u = ((const ushort4*)p)[i >> 2];
  float4 r;
  r.x = bf2f(u.x); r.y = bf2f(u.y); r.z = bf2f(u.z); r.w = bf2f(u.w);
  return r;
}
__device__ __forceinline__ unsigned short f2bf(float x) {   // RNE
  unsigned u = __float_as_uint(x);
  u += 0x7FFFu + ((u >> 16) & 1u);
  return (unsigned short)(u >> 16);
}

// ---------------- bool-encoding detection ----------------
__device__ int detect_bool_mode(const unsigned char* p) {
  if (p[0] == 0x80 && p[1] == 0x3F) return 2;   // bf16
  if (p[0] == 0x00 && p[1] == 0x3C) return 4;   // fp16
  if (p[0] == 0x00 && p[3] == 0x3F) return 3;   // fp32
  for (int i = 0; i < 64; i += 4)               // u8 vs int32
    if (p[i + 1] | p[i + 2] | p[i + 3]) return 1;
  return 0;                                     // int32
}
__device__ __forceinline__ bool bool_at(const unsigned char* p, int mode, size_t i) {
  switch (mode) {
    case 0: return ((const int*)p)[i] != 0;
    case 1: return p[i] != 0;
    case 3: return ((const float*)p)[i] != 0.f;
    default: return ((const unsigned short*)p)[i] != 0;  // bf16/fp16
  }
}

// -------- parallel detection: one block per array/task, sampled -------------
__global__ __launch_bounds__(256) void detect_all(
    const void* q, const void* k, const void* v,
    const void* qhe, const void* qee, const void* khe, const void* kee,
    const void* vhe, const void* vee,
    const int* dist, const int* edge,
    const unsigned char* mraw, const unsigned char* fraw,
    const void* Wq, const void* bq, const void* Wk, const void* bk,
    const void* Wv, const void* bv, const void* Wo, const void* bo) {
  __shared__ float sred[256];
  __shared__ int nzs;
  const int tid = threadIdx.x;
  const int blk = blockIdx.x;

  if (blk < 17) {
    const void* arrs[17] = {q, k, v, qhe, qee, khe, kee, vhe, vee,
                            Wq, bq, Wk, bk, Wv, bv, Wo, bo};
    const int full[17] = {2097152, 2097152, 2097152, 8192, 8192, 8192, 8192,
                          8192, 8192, 262144, 512, 262144, 512, 262144, 512,
                          262144, 512};
    const int n = full[blk] < 16384 ? full[blk] : 16384;   // sampled scan
    const unsigned short* u = (const unsigned short*)arrs[blk];
    float m = 0.f;
    for (int i = tid; i < n; i += 256) {
      float x = __uint_as_float((unsigned int)u[i] << 16);
      if (x != x) x = 1e20f;
      m = fmaxf(m, fabsf(x));
    }
    sred[tid] = m;
    __syncthreads();
    for (int s = 128; s > 0; s >>= 1) {
      if (tid < s) sred[tid] = fmaxf(sred[tid], sred[tid + s]);
      __syncthreads();
    }
    if (tid == 0) g_flags[4 + blk] = (sred[0] > 1e3f) ? 1 : 0;
  } else if (blk == 17 || blk == 18) {
    const int* p = (blk == 17) ? dist : edge;
    if (tid == 0) nzs = 0;
    __syncthreads();
    int a = 0;
    for (int i = tid; i < 4096; i += 256) a |= p[2 * i + 1];
    if (a) atomicOr(&nzs, 1);
    __syncthreads();
    if (tid == 0) g_flags[blk - 17] = (nzs == 0);   // all-zero high words -> int64
  } else {
    if (tid == 0) {
      g_flags[2] = detect_bool_mode(mraw);
      g_flags[3] = detect_bool_mode(fraw);
    }
  }
}

// -------- emb prep: split q/k hop+edge embeddings into bf16 hi/lo ----------
__global__ __launch_bounds__(256) void emb_prep(
    const void* qhe, const void* khe, const void* qee, const void* kee) {
  const int blk = blockIdx.x;  // 0:qhe 1:khe 2:qee 3:kee
  const void* srcs[4] = {qhe, khe, qee, kee};
  const int flagIdx[4] = {7, 9, 8, 10};
  const int counts[4] = {32 * 512, 32 * 512, 16 * 512, 16 * 512};
  const int dsts[4] = {0, 32 * 512, 64 * 512, 80 * 512};
  const int f = g_flags[flagIdx[blk]];
  const void* src = srcs[blk];
  const int n = counts[blk], d0 = dsts[blk];
  for (int i = threadIdx.x; i < n; i += 256) {
    const float x = ldf(src, f, i);
    const unsigned short hi = f2bf(x);
    g_embh[d0 + i] = hi;
    g_embl[d0 + i] = f2bf(x - bf2f(hi));
  }
}

// -------- split q/k/v inputs into bf16 hi/lo (once) -------------------------
__global__ __launch_bounds__(256) void split_prep(
    const void* q, const void* k, const void* v) {
  const int t = blockIdx.y;
  const void* srcs[3] = {q, k, v};
  const int f = g_flags[4 + t];
  const size_t base = (size_t)t * 2097152;
  const size_t i = ((size_t)blockIdx.x * 256 + threadIdx.x) * 4;
  const float4 v4 = ldf4(srcs[t], f, i);
  ushort4 h4, l4;
  h4.x = f2bf(v4.x); l4.x = f2bf(v4.x - bf2f(h4.x));
  h4.y = f2bf(v4.y); l4.y = f2bf(v4.y - bf2f(h4.y));
  h4.z = f2bf(v4.z); l4.z = f2bf(v4.z - bf2f(h4.z));
  h4.w = f2bf(v4.w); l4.w = f2bf(v4.w - bf2f(h4.w));
  *(ushort4*)&g_inhi[base + i] = h4;
  *(ushort4*)&g_inlo[base + i] = l4;
}

// -------- transpose + split weights: W[k][n] -> W^T[n][k] hi/lo (once) ------
__global__ __launch_bounds__(256) void wt_prep(
    const void* Wq, const void* Wk, const void* Wv, const void* Wo) {
  __shared__ float t[64][65];
  const int mat = blockIdx.y;
  const void* srcs[4] = {Wq, Wk, Wv, Wo};
  const int fIdx[4] = {13, 15, 17, 19};
  const int f = g_flags[fIdx[mat]];
  const void* W = srcs[mat];
  const int k0 = (blockIdx.x >> 3) * 64, n0 = (blockIdx.x & 7) * 64;
  const int tid = threadIdx.x;
  const int r = tid >> 4, c4 = (tid & 15) * 4;
#pragma unroll
  for (int i = 0; i < 4; ++i) {
    const float4 v4 = ldf4(W, f, (size_t)(k0 + r + i * 16) * 512 + n0 + c4);
    t[r + i * 16][c4] = v4.x;
    t[r + i * 16][c4 + 1] = v4.y;
    t[r + i * 16][c4 + 2] = v4.z;
    t[r + i * 16][c4 + 3] = v4.w;
  }
  __syncthreads();
  unsigned short* dh = g_wth + (size_t)mat * 262144;
  unsigned short* dl = g_wtl + (size_t)mat * 262144;
#pragma unroll
  for (int i = 0; i < 4; ++i) {
    const int rn = r + i * 16;
    ushort4 h4, l4;
    const float v0 = t[c4][rn], v1 = t[c4 + 1][rn];
    const float v2 = t[c4 + 2][rn], v3 = t[c4 + 3][rn];
    h4.x = f2bf(v0); l4.x = f2bf(v0 - bf2f(h4.x));
    h4.y = f2bf(v1); l4.y = f2bf(v1 - bf2f(h4.y));
    h4.z = f2bf(v2); l4.z = f2bf(v2 - bf2f(h4.z));
    h4.w = f2bf(v3); l4.w = f2bf(v3 - bf2f(h4.w));
    *(ushort4*)&dh[(size_t)(n0 + rn) * 512 + k0 + c4] = h4;
    *(ushort4*)&dl[(size_t)(n0 + rn) * 512 + k0 + c4] = l4;
  }
}

// -------- shared GEMM body: 64x64 tile, K-step 32, hi/lo triple MFMA --------
template <int MODE_SEL>
__device__ __forceinline__ void gemm_body(
    const unsigned short* Ahi, const unsigned short* Alo,
    const unsigned short* Wth, const unsigned short* Wtl,
    const void* bias, int bF, float* dst, int mode, int m0, int n0) {
  __shared__ unsigned short As_hi[64][40];
  __shared__ unsigned short As_lo[64][40];
  __shared__ unsigned short Wt_hi[64][40];
  __shared__ unsigned short Wt_lo[64][40];
  const int tid = threadIdx.x;
  const int w = tid >> 6, l = tid & 63, c = l & 15, g = l >> 4;
  const int wr = w >> 1, wc = w & 1;
  const int sr = tid >> 2, sc = (tid & 3) * 8;

  f32x4 acc[2][2] = {{{0.f, 0.f, 0.f, 0.f}, {0.f, 0.f, 0.f, 0.f}},
                     {{0.f, 0.f, 0.f, 0.f}, {0.f, 0.f, 0.f, 0.f}}};

  const size_t ga = (size_t)(m0 + sr) * 512 + sc;
  const size_t gw = (size_t)(n0 + sr) * 512 + sc;
  bf16x8 pa_h = *(const bf16x8*)(Ahi + ga);
  bf16x8 pa_l = *(const bf16x8*)(Alo + ga);
  bf16x8 pw_h = *(const bf16x8*)(Wth + gw);
  bf16x8 pw_l = *(const bf16x8*)(Wtl + gw);

  for (int k0 = 0; k0 < 512; k0 += 32) {
    __syncthreads();
    *(bf16x8*)&As_hi[sr][sc] = pa_h;
    *(bf16x8*)&As_lo[sr][sc] = pa_l;
    *(bf16x8*)&Wt_hi[sr][sc] = pw_h;
    *(bf16x8*)&Wt_lo[sr][sc] = pw_l;
    __syncthreads();
    if (k0 < 480) {   // prefetch next K-tile; overlaps with MFMAs below
      pa_h = *(const bf16x8*)(Ahi + ga + k0 + 32);
      pa_l = *(const bf16x8*)(Alo + ga + k0 + 32);
      pw_h = *(const bf16x8*)(Wth + gw + k0 + 32);
      pw_l = *(const bf16x8*)(Wtl + gw + k0 + 32);
    }
#pragma unroll
    for (int mi = 0; mi < 2; ++mi) {
      const bf16x8 ah = *(const bf16x8*)&As_hi[wr * 32 + mi * 16 + c][g * 8];
      const bf16x8 al = *(const bf16x8*)&As_lo[wr * 32 + mi * 16 + c][g * 8];
#pragma unroll
      for (int nj = 0; nj < 2; ++nj) {
        const bf16x8 wh = *(const bf16x8*)&Wt_hi[wc * 32 + nj * 16 + c][g * 8];
        const bf16x8 wl = *(const bf16x8*)&Wt_lo[wc * 32 + nj * 16 + c][g * 8];
        acc[mi][nj] = MFMA16(ah, wh, acc[mi][nj]);
        acc[mi][nj] = MFMA16(al, wh, acc[mi][nj]);
        acc[mi][nj] = MFMA16(ah, wl, acc[mi][nj]);
      }
    }
  }
#pragma unroll
  for (int mi = 0; mi < 2; ++mi)
#pragma unroll
    for (int nj = 0; nj < 2; ++nj)
#pragma unroll
      for (int r = 0; r < 4; ++r) {
        const int m = m0 + wr * 32 + mi * 16 + 4 * g + r;
        const int n = n0 + wc * 32 + nj * 16 + c;
        const float v2 = acc[mi][nj][r] + ldf(bias, bF, n);
        if (MODE_SEL == 3) {
          dst[(size_t)m * 512 + n] = v2;
        } else {
          const int b = m >> 9, s = m & 511, h = n >> 6, d = n & 63;
          const unsigned short hi = f2bf(v2);
          const unsigned short lo = f2bf(v2 - bf2f(hi));
          if (mode == 0) {
            const size_t i0 = (((size_t)(b * nH + h) * nS) + s) * nD + d;
            g_qhi[i0] = hi; g_qlo[i0] = lo;
          } else if (mode == 1) {
            const size_t i0 = (((size_t)(b * nH + h) * nS) + s) * nD + d;
            g_khi[i0] = hi; g_klo[i0] = lo;
          } else {
            const size_t i0 = (((size_t)(b * nH + h) * nD) + d) * nS + s;
            g_vhiT[i0] = hi; g_vloT[i0] = lo;
          }
        }
      }
}

// Q,K,V projections merged in one dispatch: grid (8, 192), 6x the resident blocks
__global__ __launch_bounds__(256, 4) void gemm_qkv(
    const unsigned short* __restrict__ inhi, const unsigned short* __restrict__ inlo,
    const unsigned short* __restrict__ wth, const unsigned short* __restrict__ wtl,
    const void* __restrict__ bq, const void* __restrict__ bk,
    const void* __restrict__ bv) {
  const int mat = blockIdx.y >> 6;              // 0=q 1=k 2=v
  const int m0 = (blockIdx.y & 63) * 64, n0 = blockIdx.x * 64;
  const void* bias = (mat == 0) ? bq : (mat == 1) ? bk : bv;
  const int bF = g_flags[14 + 2 * mat];
  gemm_body<0>(inhi + (size_t)mat * 2097152, inlo + (size_t)mat * 2097152,
               wth + (size_t)mat * 262144, wtl + (size_t)mat * 262144,
               bias, bF, nullptr, mat, m0, n0);
}

// output projection (fp32 -> dst)
__global__ __launch_bounds__(256, 4) void gemm_out(
    const unsigned short* __restrict__ Ahi, const unsigned short* __restrict__ Alo,
    const unsigned short* __restrict__ Wth, const unsigned short* __restrict__ Wtl,
    const void* __restrict__ bias, float* __restrict__ dst) {
  gemm_body<3>(Ahi, Alo, Wth, Wtl, bias, g_flags[20], dst, 3,
               blockIdx.y * 64, blockIdx.x * 64);
}

// ---------------- fused MFMA attention ---------------------------------------
// One block per (bh, 16-query tile), 4 waves. Scores transposed (S^T=mfma(K,Q^T))
// -> register softmax. Single 16KB kvbuf (K chunks then V chunks) keeps LDS at
// 40KB -> 4 blocks/CU (16 waves); inter-block overlap hides staging stalls.
__global__ __launch_bounds__(256, 4) void attn_kernel(
    const int* __restrict__ dist, const int* __restrict__ edge,
    const unsigned char* __restrict__ mraw, const unsigned char* __restrict__ fraw,
    const void* __restrict__ vhe, const void* __restrict__ vee) {
  __shared__ unsigned short kvbuf[8192];     // K: hi@[0,4096) lo@[4096,8192); V-hi: full
  __shared__ unsigned short plds[16][520];   // d | e<<5 | keep<<9 ; overlaid by x_s
  __shared__ float chop_s[16][33];
  __shared__ float cedge_s[16][17];
  __shared__ float vha_s[16][33];
  __shared__ float vea_s[16][17];
  __shared__ float red_s[16][4];
  __shared__ float red2_s[16][4];
  __shared__ float rinv_s[16];

  // XCD-aware swizzle: 8 consecutive slots per XCD share batch b -> L2 locality
  const int id = blockIdx.x;
  const int bh = (id & 7) * 8 + ((id >> 3) & 7);
  const int qt = id >> 6;
  const int b = bh >> 3, h = bh & 7;
  const int q0 = qt * 16;
  const int tid = threadIdx.x;
  const int w = tid >> 6, l = tid & 63, c = l & 15, g = l >> 4;

  const int d64 = g_flags[0], e64 = g_flags[1];
  const int mmode = g_flags[2], fmode = g_flags[3];
  const int fvhe = g_flags[11], fvee = g_flags[12];

  for (int i = tid; i < 16 * 33; i += 256) (&vha_s[0][0])[i] = 0.f;
  for (int i = tid; i < 16 * 17; i += 256) (&vea_s[0][0])[i] = 0.f;

  auto stageK = [&](int ch) {
#pragma unroll
    for (int it = 0; it < 2; ++it) {
      const int e = (tid << 3) + (it << 11);
      const int r = e >> 6, d0 = e & 63;
      const size_t src = (((size_t)bh * nS) + ch * 64 + r) * nD + d0;
      const int dsti = (r << 6) + (((d0 >> 3) ^ (r & 7)) << 3);
      *(bf16x8*)&kvbuf[dsti] = *(const bf16x8*)(g_khi + src);
      *(bf16x8*)&kvbuf[4096 + dsti] = *(const bf16x8*)(g_klo + src);
    }
  };
  auto stageV = [&](int p) {
#pragma unroll
    for (int it = 0; it < 4; ++it) {
      const int e = (tid << 3) + (it << 11);
      const int d = e >> 7, colc = e & 127;
      const size_t src = (((size_t)bh * nD) + d) * nS + (p << 7) + colc;
      const int dsti = (d << 7) + (((colc >> 3) ^ (d & 15)) << 3);
      *(bf16x8*)&kvbuf[dsti] = *(const bf16x8*)(g_vhiT + src);
    }
  };

  // ---- stage packed (dist,edge,keep) metadata, coalesced -------------------
  const size_t rowbase = ((size_t)b * nS + q0) * nS;
  for (int j4 = tid; j4 < 2048; j4 += 256) {
    const int j = j4 * 4, r = j >> 9, c1 = j & 511;
    int dv[4], ev[4];
    if (!d64) {
      const int4 t = ((const int4*)(dist + rowbase))[j4];
      dv[0] = t.x & 31; dv[1] = t.y & 31; dv[2] = t.z & 31; dv[3] = t.w & 31;
    } else {
      const int4 t0 = ((const int4*)(dist + 2 * rowbase))[2 * j4];
      const int4 t1 = ((const int4*)(dist + 2 * rowbase))[2 * j4 + 1];
      dv[0] = t0.x & 31; dv[1] = t0.z & 31; dv[2] = t1.x & 31; dv[3] = t1.z & 31;
    }
    if (!e64) {
      const int4 t = ((const int4*)(edge + rowbase))[j4];
      ev[0] = t.x & 15; ev[1] = t.y & 15; ev[2] = t.z & 15; ev[3] = t.w & 15;
    } else {
      const int4 t0 = ((const int4*)(edge + 2 * rowbase))[2 * j4];
      const int4 t1 = ((const int4*)(edge + 2 * rowbase))[2 * j4 + 1];
      ev[0] = t0.x & 15; ev[1] = t0.z & 15; ev[2] = t1.x & 15; ev[3] = t1.z & 15;
    }
    ushort4 pw;
    unsigned short* pp = (unsigned short*)&pw;
#pragma unroll
    for (int t = 0; t < 4; ++t) {
      const bool keep = (h < 4) ? bool_at(mraw, mmode, (size_t)b * nS + c1 + t)
                                : bool_at(fraw, fmode, rowbase + j + t);
      pp[t] = (unsigned short)(dv[t] | (ev[t] << 5) | ((int)keep << 9));
    }
    *(ushort4*)&plds[r][c1] = pw;
  }

  // Q fragments (lane: q-row=c, d=g*8..+7 [+32])
  const size_t qbase = (((size_t)bh * nS) + q0 + c) * nD + g * 8;
  const bf16x8 qh0 = *(const bf16x8*)(g_qhi + qbase);
  const bf16x8 qh1 = *(const bf16x8*)(g_qhi + qbase + 32);
  const bf16x8 ql0 = *(const bf16x8*)(g_qlo + qbase);
  const bf16x8 ql1 = *(const bf16x8*)(g_qlo + qbase + 32);

  // ---- Phase 0: bias tables via MFMA. waves 0,1: hop t 0-15/16-31; wave 2: edge
  if (w < 3) {
    const bool isEdge = (w == 2);
    const int tb = (w == 1) ? 16 : 0;
    const size_t qe0 = (isEdge ? (size_t)64 * 512 : 0) + (size_t)(tb + c) * 512 + h * 64;
    const size_t ke0 = (isEdge ? (size_t)80 * 512 : (size_t)32 * 512) + (size_t)(tb + c) * 512 + h * 64;
    f32x4 acc = {0.f, 0.f, 0.f, 0.f};
#pragma unroll
    for (int dh = 0; dh < 2; ++dh) {
      const bf16x8 qhh = dh ? qh1 : qh0;
      const bf16x8 qll = dh ? ql1 : ql0;
      const bf16x8 khq = *(const bf16x8*)(g_khi + qbase + dh * 32);
      const bf16x8 klq = *(const bf16x8*)(g_klo + qbase + dh * 32);
      const bf16x8 eqh = *(const bf16x8*)(g_embh + qe0 + dh * 32 + g * 8);
      const bf16x8 eql = *(const bf16x8*)(g_embl + qe0 + dh * 32 + g * 8);
      const bf16x8 ekh = *(const bf16x8*)(g_embh + ke0 + dh * 32 + g * 8);
      const bf16x8 ekl = *(const bf16x8*)(g_embl + ke0 + dh * 32 + g * 8);
      acc = MFMA16(qhh, eqh, acc);
      acc = MFMA16(qll, eqh, acc);
      acc = MFMA16(qhh, eql, acc);
      acc = MFMA16(khq, ekh, acc);
      acc = MFMA16(klq, ekh, acc);
      acc = MFMA16(khq, ekl, acc);
    }
    if (!isEdge) {
#pragma unroll
      for (int r = 0; r < 4; ++r) chop_s[4 * g + r][tb + c] = acc[r];
    } else {
#pragma unroll
      for (int r = 0; r < 4; ++r) cedge_s[4 * g + r][c] = acc[r];
    }
  }

  stageK(0);
  __syncthreads();   // barrier A (covers chop/cedge + K chunk 0 + plds)

  // ---- Phase A: S^T tiles from LDS K chunks --------------------------------
  f32x4 pS[8];
  const int sw8 = c & 7;
  for (int ch = 0; ch < 8; ++ch) {
    const int a0 = (w * 16 + c) << 6;
    f32x4 acc = {0.f, 0.f, 0.f, 0.f};
    {
      const int o0 = a0 + ((g ^ sw8) << 3);
      const int o1 = a0 + (((4 + g) ^ sw8) << 3);
      const bf16x8 kh0 = *(const bf16x8*)&kvbuf[o0];
      const bf16x8 kl0 = *(const bf16x8*)&kvbuf[4096 + o0];
      const bf16x8 kh1 = *(const bf16x8*)&kvbuf[o1];
      const bf16x8 kl1 = *(const bf16x8*)&kvbuf[4096 + o1];
      acc = MFMA16(kh0, qh0, acc);
      acc = MFMA16(kl0, qh0, acc);
      acc = MFMA16(kh0, ql0, acc);
      acc = MFMA16(kh1, qh1, acc);
      acc = MFMA16(kl1, qh1, acc);
      acc = MFMA16(kh1, ql1, acc);
    }
    const int key0 = ch * 64 + w * 16 + 4 * g;
    const ushort4 pv4 = *(const ushort4*)&plds[c][key0];
    const unsigned short pp[4] = {pv4.x, pv4.y, pv4.z, pv4.w};
#pragma unroll
    for (int r = 0; r < 4; ++r) {
      const float s = (acc[r] + chop_s[c][pp[r] & 31] +
                       cedge_s[c][(pp[r] >> 5) & 15]) * SCALE;
      pS[ch][r] = (pp[r] & 512) ? s : NEGINF;
    }
    __syncthreads();   // chunk consumed
    if (ch < 7) {
      stageK(ch + 1);
      __syncthreads();   // next chunk staged
    }
  }

  // ---- Phase B: softmax across registers + bin scatter ---------------------
  float mx = NEGINF;
#pragma unroll
  for (int kt = 0; kt < 8; ++kt)
#pragma unroll
    for (int r = 0; r < 4; ++r) mx = fmaxf(mx, pS[kt][r]);
  mx = fmaxf(mx, __shfl_xor(mx, 16));
  mx = fmaxf(mx, __shfl_xor(mx, 32));
  if (l < 16) red_s[c][w] = mx;
  stageV(0);         // kvbuf free (last barrier in Phase A); hides under softmax
  __syncthreads();   // barrier B: red_s visible + V0 staged
  const float M = fmaxf(fmaxf(red_s[c][0], red_s[c][1]),
                        fmaxf(red_s[c][2], red_s[c][3]));
  float sum = 0.f;
#pragma unroll
  for (int kt = 0; kt < 8; ++kt) {
    const int key0 = kt * 64 + w * 16 + 4 * g;
    const ushort4 pv4 = *(const ushort4*)&plds[c][key0];
    const unsigned short pp[4] = {pv4.x, pv4.y, pv4.z, pv4.w};
#pragma unroll
    for (int r = 0; r < 4; ++r) {
      const float pv = __expf(pS[kt][r] - M);
      pS[kt][r] = pv;
      sum += pv;
      atomicAdd(&vha_s[c][pp[r] & 31], pv);
      atomicAdd(&vea_s[c][(pp[r] >> 5) & 15], pv);
    }
  }
  sum += __shfl_xor(sum, 16);
  sum += __shfl_xor(sum, 32);
  if (l < 16) red2_s[c][w] = sum;
  // pack P to bf16 pairs
  int pk[8][2];
#pragma unroll
  for (int kt = 0; kt < 8; ++kt) {
    pk[kt][0] = ((int)f2bf(pS[kt][1]) << 16) | (int)f2bf(pS[kt][0]);
    pk[kt][1] = ((int)f2bf(pS[kt][3]) << 16) | (int)f2bf(pS[kt][2]);
  }
  __syncthreads();   // barrier C: plds dead from here
  float (*x_s)[17] = reinterpret_cast<float(*)[17]>(&plds[0][0]);  // overlay
  for (int i = tid; i < 64 * 17; i += 256) (&x_s[0][0])[i] = 0.f;
  if (w == 0 && l < 16) {
    const float tot = red2_s[c][0] + red2_s[c][1] + red2_s[c][2] + red2_s[c][3];
    rinv_s[c] = 1.0f / tot;
  }
  __syncthreads();   // barrier C2: x_s zeroed, rinv visible

  // ---- Phase C: out^T += V^T @ P^T. V-hi from LDS chunks; V-lo global ------
  f32x4 oacc[4] = {{0.f, 0.f, 0.f, 0.f}, {0.f, 0.f, 0.f, 0.f},
                   {0.f, 0.f, 0.f, 0.f}, {0.f, 0.f, 0.f, 0.f}};
  const int srcA = ((g & 1) * 2) * 16 + c;
  const int srcB = srcA + 16;
  const bool hi2 = (g >> 1) != 0;
  for (int p = 0; p < 4; ++p) {
    // build B-fragment of P^T for this 32-key step
    const int t0d0 = __shfl(pk[2 * p][0], srcA);
    const int t1d0 = __shfl(pk[2 * p + 1][0], srcA);
    const int t0d1 = __shfl(pk[2 * p][1], srcA);
    const int t1d1 = __shfl(pk[2 * p + 1][1], srcA);
    const int t0d0b = __shfl(pk[2 * p][0], srcB);
    const int t1d0b = __shfl(pk[2 * p + 1][0], srcB);
    const int t0d1b = __shfl(pk[2 * p][1], srcB);
    const int t1d1b = __shfl(pk[2 * p + 1][1], srcB);
    union { int i[4]; bf16x8 v; } bu;
    bu.i[0] = hi2 ? t1d0 : t0d0;
    bu.i[1] = hi2 ? t1d1 : t0d1;
    bu.i[2] = hi2 ? t1d0b : t0d0b;
    bu.i[3] = hi2 ? t1d1b : t0d1b;
    // k-idx g*8+j <-> key p*128 + (g>>1)*64 + w*16 + (g&1)*8 + j
    const int col16 = (w << 1) + (g & 1) + ((g >> 1) << 3);
    const int j0 = (p << 7) + ((g >> 1) << 6) + (w << 4) + ((g & 1) << 3);
#pragma unroll
    for (int t = 0; t < 4; ++t) {
      const int row = t * 16 + c;
      const bf16x8 vh_ = *(const bf16x8*)&kvbuf[(row << 7) + ((col16 ^ c) << 3)];
      const bf16x8 vl_ = *(const bf16x8*)(g_vloT + (((size_t)bh * nD) + row) * nS + j0);
      oacc[t] = MFMA16(vh_, bu.v, oacc[t]);
      oacc[t] = MFMA16(vl_, bu.v, oacc[t]);
    }
    __syncthreads();   // V chunk consumed
    if (p < 3) {
      stageV(p + 1);
      __syncthreads();   // next chunk staged
    }
  }
#pragma unroll
  for (int t = 0; t < 4; ++t)
#pragma unroll
    for (int r = 0; r < 4; ++r)
      atomicAdd(&x_s[t * 16 + 4 * g + r][c], oacc[t][r]);
  __syncthreads();   // barrier D

  // ---- Tail: add bin-embedding terms, normalize, store hi/lo bf16 ----------
  {
    const int d = tid & 63, qq = tid >> 6;
    float val[4];
#pragma unroll
    for (int j = 0; j < 4; ++j) val[j] = x_s[d][qq + 4 * j];
    for (int t = 0; t < THOP; ++t) {
      const float e = ldf(vhe, fvhe, (size_t)t * nHID + h * 64 + d);
#pragma unroll
      for (int j = 0; j < 4; ++j) val[j] += vha_s[qq + 4 * j][t] * e;
    }
    for (int t = 0; t < TEDGE; ++t) {
      const float e = ldf(vee, fvee, (size_t)t * nHID + h * 64 + d);
#pragma unroll
      for (int j = 0; j < 4; ++j) val[j] += vea_s[qq + 4 * j][t] * e;
    }
#pragma unroll
    for (int j = 0; j < 4; ++j) {
      const int q = qq + 4 * j;
      const float xv = val[j] * rinv_s[q];
      const unsigned short hi = f2bf(xv);
      const size_t i0 = ((size_t)b * nS + q0 + q) * nHID + h * 64 + d;
      g_xhi[i0] = hi;
      g_xlo[i0] = f2bf(xv - bf2f(hi));
    }
  }
}

// ---------------- launcher ----------------
extern "C" void kernel_launch(void* const* d_in, const int* in_sizes, int n_in,
                              void* d_out, int out_size, void* d_ws, size_t ws_size,
                              hipStream_t stream) {
  const void* q   = d_in[0];
  const void* k   = d_in[1];
  const void* v   = d_in[2];
  const void* qhe = d_in[3];
  const void* qee = d_in[4];
  const void* khe = d_in[5];
  const void* kee = d_in[6];
  const void* vhe = d_in[7];
  const void* vee = d_in[8];
  const int* dist = (const int*)d_in[9];
  const int* edge = (const int*)d_in[10];
  const unsigned char* mraw = (const unsigned char*)d_in[11];
  const unsigned char* fraw = (const unsigned char*)d_in[12];
  const void* Wq = d_in[13];
  const void* bq = d_in[14];
  const void* Wk = d_in[15];
  const void* bk = d_in[16];
  const void* Wv = d_in[17];
  const void* bv = d_in[18];
  const void* Wo = d_in[19];
  const void* bo = d_in[20];

  detect_all<<<20, 256, 0, stream>>>(q, k, v, qhe, qee, khe, kee, vhe, vee,
                                     dist, edge, mraw, fraw,
                                     Wq, bq, Wk, bk, Wv, bv, Wo, bo);
  emb_prep<<<4, 256, 0, stream>>>(qhe, khe, qee, kee);
  split_prep<<<dim3(2048, 3), 256, 0, stream>>>(q, k, v);
  wt_prep<<<dim3(64, 4), 256, 0, stream>>>(Wq, Wk, Wv, Wo);

  unsigned short* inhi; hipGetSymbolAddress((void**)&inhi, HIP_SYMBOL(g_inhi));
  unsigned short* inlo; hipGetSymbolAddress((void**)&inlo, HIP_SYMBOL(g_inlo));
  unsigned short* wth;  hipGetSymbolAddress((void**)&wth,  HIP_SYMBOL(g_wth));
  unsigned short* wtl;  hipGetSymbolAddress((void**)&wtl,  HIP_SYMBOL(g_wtl));
  unsigned short* xhi;  hipGetSymbolAddress((void**)&xhi,  HIP_SYMBOL(g_xhi));
  unsigned short* xlo;  hipGetSymbolAddress((void**)&xlo,  HIP_SYMBOL(g_xlo));

  gemm_qkv<<<dim3(8, 192), 256, 0, stream>>>(inhi, inlo, wth, wtl, bq, bk, bv);
  attn_kernel<<<2048, 256, 0, stream>>>(dist, edge, mraw, fraw, vhe, vee);
  gemm_out<<<dim3(8, 64), 256, 0, stream>>>(xhi, xlo,
                                            wth + 3 * 262144, wtl + 3 * 262144,
                                            bo, (float*)d_out);
}

// Round 7
// 558.427 us; speedup vs baseline: 1.0922x; 1.0922x over previous
//
#include <hip/hip_runtime.h>

// ---------------- problem constants ----------------
constexpr int nB = 8, nS = 512, nH = 8, nD = 64, nHID = 512;
constexpr int THOP = 32, TEDGE = 16;
constexpr float SCALE = 0.125f;   // 64^-0.5
constexpr float NEGINF = -30000.0f;

typedef __attribute__((ext_vector_type(8))) short bf16x8;   // 8 bf16 = 4 VGPR
typedef __attribute__((ext_vector_type(4))) float f32x4;

#define MFMA16(A, B, C) __builtin_amdgcn_mfma_f32_16x16x32_bf16(A, B, C, 0, 0, 0)

// ---------------- module-scope scratch ----------------
__device__ __align__(16) unsigned short g_qhi[(size_t)nB * nH * nS * nD];  // [bh][s][d]
__device__ __align__(16) unsigned short g_qlo[(size_t)nB * nH * nS * nD];
__device__ __align__(16) unsigned short g_khi[(size_t)nB * nH * nS * nD];
__device__ __align__(16) unsigned short g_klo[(size_t)nB * nH * nS * nD];
__device__ __align__(16) unsigned short g_vhiT[(size_t)nB * nH * nD * nS]; // [bh][d][s]
__device__ __align__(16) unsigned short g_vloT[(size_t)nB * nH * nD * nS];
// hi/lo bf16 split of q/k hop+edge embeddings: qhe@0, khe@32*512, qee@64*512, kee@80*512
__device__ __align__(16) unsigned short g_embh[96 * 512];
__device__ __align__(16) unsigned short g_embl[96 * 512];
// pre-split GEMM inputs: q,k,v flattened [3][2M]
__device__ __align__(16) unsigned short g_inhi[(size_t)3 * 2097152];
__device__ __align__(16) unsigned short g_inlo[(size_t)3 * 2097152];
// pre-transposed+split weights W^T [mat][n][k], mats {Wq,Wk,Wv,Wo}
__device__ __align__(16) unsigned short g_wth[(size_t)4 * 262144];
__device__ __align__(16) unsigned short g_wtl[(size_t)4 * 262144];
// attn output, hi/lo bf16 [b*s][hid]
__device__ __align__(16) unsigned short g_xhi[(size_t)nB * nS * nHID];
__device__ __align__(16) unsigned short g_xlo[(size_t)nB * nS * nHID];
// 0:dist64 1:edge64 2:mmode 3:fmode ; dtype flags (0=bf16,1=fp32):
// 4..20 = q,k,v,qhe,qee,khe,kee,vhe,vee,Wq,bq,Wk,bk,Wv,bv,Wo,bo
__device__ int g_flags[32];

// adaptive scalar load: bf16 or fp32 element i
__device__ __forceinline__ float ldf(const void* p, int isf32, size_t i) {
  if (isf32) return ((const float*)p)[i];
  unsigned int w = (unsigned int)(((const unsigned short*)p)[i]) << 16;
  return __uint_as_float(w);
}
__device__ __forceinline__ float bf2f(unsigned short h) {
  return __uint_as_float((unsigned)h << 16);
}
__device__ __forceinline__ float4 ldf4(const void* p, int isf32, size_t i) {
  if (isf32) return ((const float4*)p)[i >> 2];
  const ushort4 u = ((const ushort4*)p)[i >> 2];
  float4 r;
  r.x = bf2f(u.x); r.y = bf2f(u.y); r.z = bf2f(u.z); r.w = bf2f(u.w);
  return r;
}
__device__ __forceinline__ unsigned short f2bf(float x) {   // RNE
  unsigned u = __float_as_uint(x);
  u += 0x7FFFu + ((u >> 16) & 1u);
  return (unsigned short)(u >> 16);
}

// ---------------- bool-encoding detection ----------------
__device__ int detect_bool_mode(const unsigned char* p) {
  if (p[0] == 0x80 && p[1] == 0x3F) return 2;   // bf16
  if (p[0] == 0x00 && p[1] == 0x3C) return 4;   // fp16
  if (p[0] == 0x00 && p[3] == 0x3F) return 3;   // fp32
  for (int i = 0; i < 64; i += 4)               // u8 vs int32
    if (p[i + 1] | p[i + 2] | p[i + 3]) return 1;
  return 0;                                     // int32
}
__device__ __forceinline__ bool bool_at(const unsigned char* p, int mode, size_t i) {
  switch (mode) {
    case 0: return ((const int*)p)[i] != 0;
    case 1: return p[i] != 0;
    case 3: return ((const float*)p)[i] != 0.f;
    default: return ((const unsigned short*)p)[i] != 0;  // bf16/fp16
  }
}

// -------- parallel detection: one block per array/task, sampled -------------
__global__ __launch_bounds__(256) void detect_all(
    const void* q, const void* k, const void* v,
    const void* qhe, const void* qee, const void* khe, const void* kee,
    const void* vhe, const void* vee,
    const int* dist, const int* edge,
    const unsigned char* mraw, const unsigned char* fraw,
    const void* Wq, const void* bq, const void* Wk, const void* bk,
    const void* Wv, const void* bv, const void* Wo, const void* bo) {
  __shared__ float sred[256];
  __shared__ int nzs;
  const int tid = threadIdx.x;
  const int blk = blockIdx.x;

  if (blk < 17) {
    const void* arrs[17] = {q, k, v, qhe, qee, khe, kee, vhe, vee,
                            Wq, bq, Wk, bk, Wv, bv, Wo, bo};
    const int full[17] = {2097152, 2097152, 2097152, 8192, 8192, 8192, 8192,
                          8192, 8192, 262144, 512, 262144, 512, 262144, 512,
                          262144, 512};
    const int n = full[blk] < 16384 ? full[blk] : 16384;   // sampled scan
    const unsigned short* u = (const unsigned short*)arrs[blk];
    float m = 0.f;
    for (int i = tid; i < n; i += 256) {
      float x = __uint_as_float((unsigned int)u[i] << 16);
      if (x != x) x = 1e20f;
      m = fmaxf(m, fabsf(x));
    }
    sred[tid] = m;
    __syncthreads();
    for (int s = 128; s > 0; s >>= 1) {
      if (tid < s) sred[tid] = fmaxf(sred[tid], sred[tid + s]);
      __syncthreads();
    }
    if (tid == 0) g_flags[4 + blk] = (sred[0] > 1e3f) ? 1 : 0;
  } else if (blk == 17 || blk == 18) {
    const int* p = (blk == 17) ? dist : edge;
    if (tid == 0) nzs = 0;
    __syncthreads();
    int a = 0;
    for (int i = tid; i < 4096; i += 256) a |= p[2 * i + 1];
    if (a) atomicOr(&nzs, 1);
    __syncthreads();
    if (tid == 0) g_flags[blk - 17] = (nzs == 0);   // all-zero high words -> int64
  } else {
    if (tid == 0) {
      g_flags[2] = detect_bool_mode(mraw);
      g_flags[3] = detect_bool_mode(fraw);
    }
  }
}

// -------- emb prep: split q/k hop+edge embeddings into bf16 hi/lo ----------
__global__ __launch_bounds__(256) void emb_prep(
    const void* qhe, const void* khe, const void* qee, const void* kee) {
  const int blk = blockIdx.x;  // 0:qhe 1:khe 2:qee 3:kee
  const void* srcs[4] = {qhe, khe, qee, kee};
  const int flagIdx[4] = {7, 9, 8, 10};
  const int counts[4] = {32 * 512, 32 * 512, 16 * 512, 16 * 512};
  const int dsts[4] = {0, 32 * 512, 64 * 512, 80 * 512};
  const int f = g_flags[flagIdx[blk]];
  const void* src = srcs[blk];
  const int n = counts[blk], d0 = dsts[blk];
  for (int i = threadIdx.x; i < n; i += 256) {
    const float x = ldf(src, f, i);
    const unsigned short hi = f2bf(x);
    g_embh[d0 + i] = hi;
    g_embl[d0 + i] = f2bf(x - bf2f(hi));
  }
}

// -------- split q/k/v inputs into bf16 hi/lo (once) -------------------------
__global__ __launch_bounds__(256) void split_prep(
    const void* q, const void* k, const void* v) {
  const int t = blockIdx.y;
  const void* srcs[3] = {q, k, v};
  const int f = g_flags[4 + t];
  const size_t base = (size_t)t * 2097152;
  const size_t i = ((size_t)blockIdx.x * 256 + threadIdx.x) * 4;
  const float4 v4 = ldf4(srcs[t], f, i);
  ushort4 h4, l4;
  h4.x = f2bf(v4.x); l4.x = f2bf(v4.x - bf2f(h4.x));
  h4.y = f2bf(v4.y); l4.y = f2bf(v4.y - bf2f(h4.y));
  h4.z = f2bf(v4.z); l4.z = f2bf(v4.z - bf2f(h4.z));
  h4.w = f2bf(v4.w); l4.w = f2bf(v4.w - bf2f(h4.w));
  *(ushort4*)&g_inhi[base + i] = h4;
  *(ushort4*)&g_inlo[base + i] = l4;
}

// -------- transpose + split weights: W[k][n] -> W^T[n][k] hi/lo (once) ------
__global__ __launch_bounds__(256) void wt_prep(
    const void* Wq, const void* Wk, const void* Wv, const void* Wo) {
  __shared__ float t[64][65];
  const int mat = blockIdx.y;
  const void* srcs[4] = {Wq, Wk, Wv, Wo};
  const int fIdx[4] = {13, 15, 17, 19};
  const int f = g_flags[fIdx[mat]];
  const void* W = srcs[mat];
  const int k0 = (blockIdx.x >> 3) * 64, n0 = (blockIdx.x & 7) * 64;
  const int tid = threadIdx.x;
  const int r = tid >> 4, c4 = (tid & 15) * 4;
#pragma unroll
  for (int i = 0; i < 4; ++i) {
    const float4 v4 = ldf4(W, f, (size_t)(k0 + r + i * 16) * 512 + n0 + c4);
    t[r + i * 16][c4] = v4.x;
    t[r + i * 16][c4 + 1] = v4.y;
    t[r + i * 16][c4 + 2] = v4.z;
    t[r + i * 16][c4 + 3] = v4.w;
  }
  __syncthreads();
  unsigned short* dh = g_wth + (size_t)mat * 262144;
  unsigned short* dl = g_wtl + (size_t)mat * 262144;
#pragma unroll
  for (int i = 0; i < 4; ++i) {
    const int rn = r + i * 16;
    ushort4 h4, l4;
    const float v0 = t[c4][rn], v1 = t[c4 + 1][rn];
    const float v2 = t[c4 + 2][rn], v3 = t[c4 + 3][rn];
    h4.x = f2bf(v0); l4.x = f2bf(v0 - bf2f(h4.x));
    h4.y = f2bf(v1); l4.y = f2bf(v1 - bf2f(h4.y));
    h4.z = f2bf(v2); l4.z = f2bf(v2 - bf2f(h4.z));
    h4.w = f2bf(v3); l4.w = f2bf(v3 - bf2f(h4.w));
    *(ushort4*)&dh[(size_t)(n0 + rn) * 512 + k0 + c4] = h4;
    *(ushort4*)&dl[(size_t)(n0 + rn) * 512 + k0 + c4] = l4;
  }
}

// -------- shared GEMM body: 64x64 tile, K-step 32, hi/lo triple MFMA --------
template <int MODE_SEL>
__device__ __forceinline__ void gemm_body(
    const unsigned short* Ahi, const unsigned short* Alo,
    const unsigned short* Wth, const unsigned short* Wtl,
    const void* bias, int bF, float* dst, int mode, int m0, int n0) {
  __shared__ unsigned short As_hi[64][40];
  __shared__ unsigned short As_lo[64][40];
  __shared__ unsigned short Wt_hi[64][40];
  __shared__ unsigned short Wt_lo[64][40];
  const int tid = threadIdx.x;
  const int w = tid >> 6, l = tid & 63, c = l & 15, g = l >> 4;
  const int wr = w >> 1, wc = w & 1;
  const int sr = tid >> 2, sc = (tid & 3) * 8;

  f32x4 acc[2][2] = {{{0.f, 0.f, 0.f, 0.f}, {0.f, 0.f, 0.f, 0.f}},
                     {{0.f, 0.f, 0.f, 0.f}, {0.f, 0.f, 0.f, 0.f}}};

  const size_t ga = (size_t)(m0 + sr) * 512 + sc;
  const size_t gw = (size_t)(n0 + sr) * 512 + sc;
  bf16x8 pa_h = *(const bf16x8*)(Ahi + ga);
  bf16x8 pa_l = *(const bf16x8*)(Alo + ga);
  bf16x8 pw_h = *(const bf16x8*)(Wth + gw);
  bf16x8 pw_l = *(const bf16x8*)(Wtl + gw);

  for (int k0 = 0; k0 < 512; k0 += 32) {
    __syncthreads();
    *(bf16x8*)&As_hi[sr][sc] = pa_h;
    *(bf16x8*)&As_lo[sr][sc] = pa_l;
    *(bf16x8*)&Wt_hi[sr][sc] = pw_h;
    *(bf16x8*)&Wt_lo[sr][sc] = pw_l;
    __syncthreads();
    if (k0 < 480) {   // prefetch next K-tile; overlaps with MFMAs below
      pa_h = *(const bf16x8*)(Ahi + ga + k0 + 32);
      pa_l = *(const bf16x8*)(Alo + ga + k0 + 32);
      pw_h = *(const bf16x8*)(Wth + gw + k0 + 32);
      pw_l = *(const bf16x8*)(Wtl + gw + k0 + 32);
    }
#pragma unroll
    for (int mi = 0; mi < 2; ++mi) {
      const bf16x8 ah = *(const bf16x8*)&As_hi[wr * 32 + mi * 16 + c][g * 8];
      const bf16x8 al = *(const bf16x8*)&As_lo[wr * 32 + mi * 16 + c][g * 8];
#pragma unroll
      for (int nj = 0; nj < 2; ++nj) {
        const bf16x8 wh = *(const bf16x8*)&Wt_hi[wc * 32 + nj * 16 + c][g * 8];
        const bf16x8 wl = *(const bf16x8*)&Wt_lo[wc * 32 + nj * 16 + c][g * 8];
        acc[mi][nj] = MFMA16(ah, wh, acc[mi][nj]);
        acc[mi][nj] = MFMA16(al, wh, acc[mi][nj]);
        acc[mi][nj] = MFMA16(ah, wl, acc[mi][nj]);
      }
    }
  }
#pragma unroll
  for (int mi = 0; mi < 2; ++mi)
#pragma unroll
    for (int nj = 0; nj < 2; ++nj)
#pragma unroll
      for (int r = 0; r < 4; ++r) {
        const int m = m0 + wr * 32 + mi * 16 + 4 * g + r;
        const int n = n0 + wc * 32 + nj * 16 + c;
        const float v2 = acc[mi][nj][r] + ldf(bias, bF, n);
        if (MODE_SEL == 3) {
          dst[(size_t)m * 512 + n] = v2;
        } else {
          const int b = m >> 9, s = m & 511, h = n >> 6, d = n & 63;
          const unsigned short hi = f2bf(v2);
          const unsigned short lo = f2bf(v2 - bf2f(hi));
          if (mode == 0) {
            const size_t i0 = (((size_t)(b * nH + h) * nS) + s) * nD + d;
            g_qhi[i0] = hi; g_qlo[i0] = lo;
          } else if (mode == 1) {
            const size_t i0 = (((size_t)(b * nH + h) * nS) + s) * nD + d;
            g_khi[i0] = hi; g_klo[i0] = lo;
          } else {
            const size_t i0 = (((size_t)(b * nH + h) * nD) + d) * nS + s;
            g_vhiT[i0] = hi; g_vloT[i0] = lo;
          }
        }
      }
}

// Q,K,V projections merged in one dispatch: grid (8, 192)
__global__ __launch_bounds__(256, 4) void gemm_qkv(
    const unsigned short* __restrict__ inhi, const unsigned short* __restrict__ inlo,
    const unsigned short* __restrict__ wth, const unsigned short* __restrict__ wtl,
    const void* __restrict__ bq, const void* __restrict__ bk,
    const void* __restrict__ bv) {
  const int mat = blockIdx.y >> 6;              // 0=q 1=k 2=v
  const int m0 = (blockIdx.y & 63) * 64, n0 = blockIdx.x * 64;
  const void* bias = (mat == 0) ? bq : (mat == 1) ? bk : bv;
  const int bF = g_flags[14 + 2 * mat];
  gemm_body<0>(inhi + (size_t)mat * 2097152, inlo + (size_t)mat * 2097152,
               wth + (size_t)mat * 262144, wtl + (size_t)mat * 262144,
               bias, bF, nullptr, mat, m0, n0);
}

// output projection (fp32 -> dst)
__global__ __launch_bounds__(256, 4) void gemm_out(
    const unsigned short* __restrict__ Ahi, const unsigned short* __restrict__ Alo,
    const unsigned short* __restrict__ Wth, const unsigned short* __restrict__ Wtl,
    const void* __restrict__ bias, float* __restrict__ dst) {
  gemm_body<3>(Ahi, Alo, Wth, Wtl, bias, g_flags[20], dst, 3,
               blockIdx.y * 64, blockIdx.x * 64);
}

// ---------------- fused MFMA attention ---------------------------------------
// One block per (bh, 16-query tile), 4 waves. Scores transposed (S^T=mfma(K,Q^T))
// -> register softmax. 40KB LDS, __launch_bounds__(256,3): ~168 total regs/wave
// (no spill, cf. r6's 64-reg 249MB-spill disaster) at 3 blocks/CU.
// T14 async staging: global->reg loads issued a phase early, reg->LDS writes
// just before use; HBM latency hides under MFMA compute.
__global__ __launch_bounds__(256, 3) void attn_kernel(
    const int* __restrict__ dist, const int* __restrict__ edge,
    const unsigned char* __restrict__ mraw, const unsigned char* __restrict__ fraw,
    const void* __restrict__ vhe, const void* __restrict__ vee) {
  __shared__ unsigned short kvbuf[8192];     // K: hi@[0,4096) lo@[4096,8192); V-hi: full
  __shared__ unsigned short plds[16][520];   // d | e<<5 | keep<<9 ; overlaid by x_s
  __shared__ float chop_s[16][33];
  __shared__ float cedge_s[16][17];
  __shared__ float vha_s[16][33];
  __shared__ float vea_s[16][17];
  __shared__ float red_s[16][4];
  __shared__ float red2_s[16][4];
  __shared__ float rinv_s[16];

  // XCD-aware swizzle: 8 consecutive slots per XCD share batch b -> L2 locality
  const int id = blockIdx.x;
  const int bh = (id & 7) * 8 + ((id >> 3) & 7);
  const int qt = id >> 6;
  const int b = bh >> 3, h = bh & 7;
  const int q0 = qt * 16;
  const int tid = threadIdx.x;
  const int w = tid >> 6, l = tid & 63, c = l & 15, g = l >> 4;

  const int d64 = g_flags[0], e64 = g_flags[1];
  const int mmode = g_flags[2], fmode = g_flags[3];
  const int fvhe = g_flags[11], fvee = g_flags[12];

  for (int i = tid; i < 16 * 33; i += 256) (&vha_s[0][0])[i] = 0.f;
  for (int i = tid; i < 16 * 17; i += 256) (&vea_s[0][0])[i] = 0.f;

  // ---- T14 reg-staging state + helpers -------------------------------------
  const int e0 = tid << 3;
  const int kr0 = e0 >> 6, kd0 = e0 & 63;          // K: rows kr0 / kr0+32
  const int vd0 = e0 >> 7, vcol = e0 & 127;        // V: d rows vd0+16*it
  bf16x8 rkh0, rkh1, rkl0, rkl1;                   // K staging regs (16 VGPR)
  bf16x8 rv0, rv1, rv2, rv3;                       // V staging regs (16 VGPR)

  auto loadK = [&](int ch) {
    const size_t base = ((size_t)bh * nS + ch * 64) * nD + kd0;
    rkh0 = *(const bf16x8*)(g_khi + base + (size_t)kr0 * nD);
    rkl0 = *(const bf16x8*)(g_klo + base + (size_t)kr0 * nD);
    rkh1 = *(const bf16x8*)(g_khi + base + (size_t)(kr0 + 32) * nD);
    rkl1 = *(const bf16x8*)(g_klo + base + (size_t)(kr0 + 32) * nD);
  };
  auto writeK = [&]() {
    const int dst0 = (kr0 << 6) + (((kd0 >> 3) ^ (kr0 & 7)) << 3);
    const int dst1 = ((kr0 + 32) << 6) + (((kd0 >> 3) ^ ((kr0 + 32) & 7)) << 3);
    *(bf16x8*)&kvbuf[dst0] = rkh0;
    *(bf16x8*)&kvbuf[4096 + dst0] = rkl0;
    *(bf16x8*)&kvbuf[dst1] = rkh1;
    *(bf16x8*)&kvbuf[4096 + dst1] = rkl1;
  };
  auto loadV = [&](int p) {
    const size_t base = (size_t)bh * nD * nS + (p << 7) + vcol;
    rv0 = *(const bf16x8*)(g_vhiT + base + (size_t)vd0 * nS);
    rv1 = *(const bf16x8*)(g_vhiT + base + (size_t)(vd0 + 16) * nS);
    rv2 = *(const bf16x8*)(g_vhiT + base + (size_t)(vd0 + 32) * nS);
    rv3 = *(const bf16x8*)(g_vhiT + base + (size_t)(vd0 + 48) * nS);
  };
  auto writeV = [&]() {
    const int swz = ((vcol >> 3) ^ (vd0 & 15)) << 3;   // same for all 4 (d%16 equal)
    *(bf16x8*)&kvbuf[(vd0 << 7) + swz] = rv0;
    *(bf16x8*)&kvbuf[((vd0 + 16) << 7) + swz] = rv1;
    *(bf16x8*)&kvbuf[((vd0 + 32) << 7) + swz] = rv2;
    *(bf16x8*)&kvbuf[((vd0 + 48) << 7) + swz] = rv3;
  };

  loadK(0);   // issue earliest: latency hides under metadata staging + Phase 0

  // ---- stage packed (dist,edge,keep) metadata, coalesced -------------------
  const size_t rowbase = ((size_t)b * nS + q0) * nS;
  for (int j4 = tid; j4 < 2048; j4 += 256) {
    const int j = j4 * 4, r = j >> 9, c1 = j & 511;
    int dv[4], ev[4];
    if (!d64) {
      const int4 t = ((const int4*)(dist + rowbase))[j4];
      dv[0] = t.x & 31; dv[1] = t.y & 31; dv[2] = t.z & 31; dv[3] = t.w & 31;
    } else {
      const int4 t0 = ((const int4*)(dist + 2 * rowbase))[2 * j4];
      const int4 t1 = ((const int4*)(dist + 2 * rowbase))[2 * j4 + 1];
      dv[0] = t0.x & 31; dv[1] = t0.z & 31; dv[2] = t1.x & 31; dv[3] = t1.z & 31;
    }
    if (!e64) {
      const int4 t = ((const int4*)(edge + rowbase))[j4];
      ev[0] = t.x & 15; ev[1] = t.y & 15; ev[2] = t.z & 15; ev[3] = t.w & 15;
    } else {
      const int4 t0 = ((const int4*)(edge + 2 * rowbase))[2 * j4];
      const int4 t1 = ((const int4*)(edge + 2 * rowbase))[2 * j4 + 1];
      ev[0] = t0.x & 15; ev[1] = t0.z & 15; ev[2] = t1.x & 15; ev[3] = t1.z & 15;
    }
    ushort4 pw;
    unsigned short* pp = (unsigned short*)&pw;
#pragma unroll
    for (int t = 0; t < 4; ++t) {
      const bool keep = (h < 4) ? bool_at(mraw, mmode, (size_t)b * nS + c1 + t)
                                : bool_at(fraw, fmode, rowbase + j + t);
      pp[t] = (unsigned short)(dv[t] | (ev[t] << 5) | ((int)keep << 9));
    }
    *(ushort4*)&plds[r][c1] = pw;
  }

  // Q fragments (lane: q-row=c, d=g*8..+7 [+32])
  const size_t qbase = (((size_t)bh * nS) + q0 + c) * nD + g * 8;
  const bf16x8 qh0 = *(const bf16x8*)(g_qhi + qbase);
  const bf16x8 qh1 = *(const bf16x8*)(g_qhi + qbase + 32);
  const bf16x8 ql0 = *(const bf16x8*)(g_qlo + qbase);
  const bf16x8 ql1 = *(const bf16x8*)(g_qlo + qbase + 32);

  // ---- Phase 0: bias tables via MFMA. waves 0,1: hop t 0-15/16-31; wave 2: edge
  if (w < 3) {
    const bool isEdge = (w == 2);
    const int tb = (w == 1) ? 16 : 0;
    const size_t qe0 = (isEdge ? (size_t)64 * 512 : 0) + (size_t)(tb + c) * 512 + h * 64;
    const size_t ke0 = (isEdge ? (size_t)80 * 512 : (size_t)32 * 512) + (size_t)(tb + c) * 512 + h * 64;
    f32x4 acc = {0.f, 0.f, 0.f, 0.f};
#pragma unroll
    for (int dh = 0; dh < 2; ++dh) {
      const bf16x8 qhh = dh ? qh1 : qh0;
      const bf16x8 qll = dh ? ql1 : ql0;
      const bf16x8 khq = *(const bf16x8*)(g_khi + qbase + dh * 32);
      const bf16x8 klq = *(const bf16x8*)(g_klo + qbase + dh * 32);
      const bf16x8 eqh = *(const bf16x8*)(g_embh + qe0 + dh * 32 + g * 8);
      const bf16x8 eql = *(const bf16x8*)(g_embl + qe0 + dh * 32 + g * 8);
      const bf16x8 ekh = *(const bf16x8*)(g_embh + ke0 + dh * 32 + g * 8);
      const bf16x8 ekl = *(const bf16x8*)(g_embl + ke0 + dh * 32 + g * 8);
      acc = MFMA16(qhh, eqh, acc);
      acc = MFMA16(qll, eqh, acc);
      acc = MFMA16(qhh, eql, acc);
      acc = MFMA16(khq, ekh, acc);
      acc = MFMA16(klq, ekh, acc);
      acc = MFMA16(khq, ekl, acc);
    }
    if (!isEdge) {
#pragma unroll
      for (int r = 0; r < 4; ++r) chop_s[4 * g + r][tb + c] = acc[r];
    } else {
#pragma unroll
      for (int r = 0; r < 4; ++r) cedge_s[4 * g + r][c] = acc[r];
    }
  }

  writeK();          // chunk 0 regs -> LDS (loads long since landed)
  __syncthreads();   // barrier A (chop/cedge + K chunk 0 + plds all visible)

  // ---- Phase A: S^T tiles; loads for ch+1 issued before computing ch -------
  f32x4 pS[8];
  const int sw8 = c & 7;
  for (int ch = 0; ch < 8; ++ch) {
    if (ch < 7) loadK(ch + 1);          // issue next-chunk loads (T14)
    const int a0 = (w * 16 + c) << 6;
    f32x4 acc = {0.f, 0.f, 0.f, 0.f};
    {
      const int o0 = a0 + ((g ^ sw8) << 3);
      const int o1 = a0 + (((4 + g) ^ sw8) << 3);
      const bf16x8 kh0 = *(const bf16x8*)&kvbuf[o0];
      const bf16x8 kl0 = *(const bf16x8*)&kvbuf[4096 + o0];
      const bf16x8 kh1 = *(const bf16x8*)&kvbuf[o1];
      const bf16x8 kl1 = *(const bf16x8*)&kvbuf[4096 + o1];
      acc = MFMA16(kh0, qh0, acc);
      acc = MFMA16(kl0, qh0, acc);
      acc = MFMA16(kh0, ql0, acc);
      acc = MFMA16(kh1, qh1, acc);
      acc = MFMA16(kl1, qh1, acc);
      acc = MFMA16(kh1, ql1, acc);
    }
    const int key0 = ch * 64 + w * 16 + 4 * g;
    const ushort4 pv4 = *(const ushort4*)&plds[c][key0];
    const unsigned short pp[4] = {pv4.x, pv4.y, pv4.z, pv4.w};
#pragma unroll
    for (int r = 0; r < 4; ++r) {
      const float s = (acc[r] + chop_s[c][pp[r] & 31] +
                       cedge_s[c][(pp[r] >> 5) & 15]) * SCALE;
      pS[ch][r] = (pp[r] & 512) ? s : NEGINF;
    }
    __syncthreads();   // chunk consumed
    if (ch < 7) {
      writeK();        // regs -> LDS (latency already hidden under MFMAs)
      __syncthreads(); // next chunk staged
    }
  }

  loadV(0);            // issue V chunk 0; lands during softmax

  // ---- Phase B: softmax across registers + bin scatter ---------------------
  float mx = NEGINF;
#pragma unroll
  for (int kt = 0; kt < 8; ++kt)
#pragma unroll
    for (int r = 0; r < 4; ++r) mx = fmaxf(mx, pS[kt][r]);
  mx = fmaxf(mx, __shfl_xor(mx, 16));
  mx = fmaxf(mx, __shfl_xor(mx, 32));
  if (l < 16) red_s[c][w] = mx;
  __syncthreads();   // barrier B
  const float M = fmaxf(fmaxf(red_s[c][0], red_s[c][1]),
                        fmaxf(red_s[c][2], red_s[c][3]));
  float sum = 0.f;
#pragma unroll
  for (int kt = 0; kt < 8; ++kt) {
    const int key0 = kt * 64 + w * 16 + 4 * g;
    const ushort4 pv4 = *(const ushort4*)&plds[c][key0];
    const unsigned short pp[4] = {pv4.x, pv4.y, pv4.z, pv4.w};
#pragma unroll
    for (int r = 0; r < 4; ++r) {
      const float pv = __expf(pS[kt][r] - M);
      pS[kt][r] = pv;
      sum += pv;
      atomicAdd(&vha_s[c][pp[r] & 31], pv);
      atomicAdd(&vea_s[c][(pp[r] >> 5) & 15], pv);
    }
  }
  sum += __shfl_xor(sum, 16);
  sum += __shfl_xor(sum, 32);
  if (l < 16) red2_s[c][w] = sum;
  // pack P to bf16 pairs
  int pk[8][2];
#pragma unroll
  for (int kt = 0; kt < 8; ++kt) {
    pk[kt][0] = ((int)f2bf(pS[kt][1]) << 16) | (int)f2bf(pS[kt][0]);
    pk[kt][1] = ((int)f2bf(pS[kt][3]) << 16) | (int)f2bf(pS[kt][2]);
  }
  writeV();          // V chunk 0 -> LDS (kvbuf free since last Phase A barrier)
  __syncthreads();   // barrier C: plds dead from here; V0 staged
  float (*x_s)[17] = reinterpret_cast<float(*)[17]>(&plds[0][0]);  // overlay
  for (int i = tid; i < 64 * 17; i += 256) (&x_s[0][0])[i] = 0.f;
  if (w == 0 && l < 16) {
    const float tot = red2_s[c][0] + red2_s[c][1] + red2_s[c][2] + red2_s[c][3];
    rinv_s[c] = 1.0f / tot;
  }
  __syncthreads();   // barrier C2: x_s zeroed, rinv visible

  // ---- Phase C: out^T += V^T @ P^T; next-chunk loads issued before compute -
  f32x4 oacc[4] = {{0.f, 0.f, 0.f, 0.f}, {0.f, 0.f, 0.f, 0.f},
                   {0.f, 0.f, 0.f, 0.f}, {0.f, 0.f, 0.f, 0.f}};
  const int srcA = ((g & 1) * 2) * 16 + c;
  const int srcB = srcA + 16;
  const bool hi2 = (g >> 1) != 0;
  for (int p = 0; p < 4; ++p) {
    if (p < 3) loadV(p + 1);            // issue next-chunk loads (T14)
    // build B-fragment of P^T for this 32-key step
    const int t0d0 = __shfl(pk[2 * p][0], srcA);
    const int t1d0 = __shfl(pk[2 * p + 1][0], srcA);
    const int t0d1 = __shfl(pk[2 * p][1], srcA);
    const int t1d1 = __shfl(pk[2 * p + 1][1], srcA);
    const int t0d0b = __shfl(pk[2 * p][0], srcB);
    const int t1d0b = __shfl(pk[2 * p + 1][0], srcB);
    const int t0d1b = __shfl(pk[2 * p][1], srcB);
    const int t1d1b = __shfl(pk[2 * p + 1][1], srcB);
    union { int i[4]; bf16x8 v; } bu;
    bu.i[0] = hi2 ? t1d0 : t0d0;
    bu.i[1] = hi2 ? t1d1 : t0d1;
    bu.i[2] = hi2 ? t1d0b : t0d0b;
    bu.i[3] = hi2 ? t1d1b : t0d1b;
    // k-idx g*8+j <-> key p*128 + (g>>1)*64 + w*16 + (g&1)*8 + j
    const int col16 = (w << 1) + (g & 1) + ((g >> 1) << 3);
    const int j0 = (p << 7) + ((g >> 1) << 6) + (w << 4) + ((g & 1) << 3);
#pragma unroll
    for (int t = 0; t < 4; ++t) {
      const int row = t * 16 + c;
      const bf16x8 vh_ = *(const bf16x8*)&kvbuf[(row << 7) + ((col16 ^ c) << 3)];
      const bf16x8 vl_ = *(const bf16x8*)(g_vloT + (((size_t)bh * nD) + row) * nS + j0);
      oacc[t] = MFMA16(vh_, bu.v, oacc[t]);
      oacc[t] = MFMA16(vl_, bu.v, oacc[t]);
    }
    __syncthreads();   // V chunk consumed
    if (p < 3) {
      writeV();        // regs -> LDS
      __syncthreads(); // next chunk staged
    }
  }
#pragma unroll
  for (int t = 0; t < 4; ++t)
#pragma unroll
    for (int r = 0; r < 4; ++r)
      atomicAdd(&x_s[t * 16 + 4 * g + r][c], oacc[t][r]);
  __syncthreads();   // barrier D

  // ---- Tail: add bin-embedding terms, normalize, store hi/lo bf16 ----------
  {
    const int d = tid & 63, qq = tid >> 6;
    float val[4];
#pragma unroll
    for (int j = 0; j < 4; ++j) val[j] = x_s[d][qq + 4 * j];
    for (int t = 0; t < THOP; ++t) {
      const float e = ldf(vhe, fvhe, (size_t)t * nHID + h * 64 + d);
#pragma unroll
      for (int j = 0; j < 4; ++j) val[j] += vha_s[qq + 4 * j][t] * e;
    }
    for (int t = 0; t < TEDGE; ++t) {
      const float e = ldf(vee, fvee, (size_t)t * nHID + h * 64 + d);
#pragma unroll
      for (int j = 0; j < 4; ++j) val[j] += vea_s[qq + 4 * j][t] * e;
    }
#pragma unroll
    for (int j = 0; j < 4; ++j) {
      const int q = qq + 4 * j;
      const float xv = val[j] * rinv_s[q];
      const unsigned short hi = f2bf(xv);
      const size_t i0 = ((size_t)b * nS + q0 + q) * nHID + h * 64 + d;
      g_xhi[i0] = hi;
      g_xlo[i0] = f2bf(xv - bf2f(hi));
    }
  }
}

// ---------------- launcher ----------------
extern "C" void kernel_launch(void* const* d_in, const int* in_sizes, int n_in,
                              void* d_out, int out_size, void* d_ws, size_t ws_size,
                              hipStream_t stream) {
  const void* q   = d_in[0];
  const void* k   = d_in[1];
  const void* v   = d_in[2];
  const void* qhe = d_in[3];
  const void* qee = d_in[4];
  const void* khe = d_in[5];
  const void* kee = d_in[6];
  const void* vhe = d_in[7];
  const void* vee = d_in[8];
  const int* dist = (const int*)d_in[9];
  const int* edge = (const int*)d_in[10];
  const unsigned char* mraw = (const unsigned char*)d_in[11];
  const unsigned char* fraw = (const unsigned char*)d_in[12];
  const void* Wq = d_in[13];
  const void* bq = d_in[14];
  const void* Wk = d_in[15];
  const void* bk = d_in[16];
  const void* Wv = d_in[17];
  const void* bv = d_in[18];
  const void* Wo = d_in[19];
  const void* bo = d_in[20];

  detect_all<<<20, 256, 0, stream>>>(q, k, v, qhe, qee, khe, kee, vhe, vee,
                                     dist, edge, mraw, fraw,
                                     Wq, bq, Wk, bk, Wv, bv, Wo, bo);
  emb_prep<<<4, 256, 0, stream>>>(qhe, khe, qee, kee);
  split_prep<<<dim3(2048, 3), 256, 0, stream>>>(q, k, v);
  wt_prep<<<dim3(64, 4), 256, 0, stream>>>(Wq, Wk, Wv, Wo);

  unsigned short* inhi; hipGetSymbolAddress((void**)&inhi, HIP_SYMBOL(g_inhi));
  unsigned short* inlo; hipGetSymbolAddress((void**)&inlo, HIP_SYMBOL(g_inlo));
  unsigned short* wth;  hipGetSymbolAddress((void**)&wth,  HIP_SYMBOL(g_wth));
  unsigned short* wtl;  hipGetSymbolAddress((void**)&wtl,  HIP_SYMBOL(g_wtl));
  unsigned short* xhi;  hipGetSymbolAddress((void**)&xhi,  HIP_SYMBOL(g_xhi));
  unsigned short* xlo;  hipGetSymbolAddress((void**)&xlo,  HIP_SYMBOL(g_xlo));

  gemm_qkv<<<dim3(8, 192), 256, 0, stream>>>(inhi, inlo, wth, wtl, bq, bk, bv);
  attn_kernel<<<2048, 256, 0, stream>>>(dist, edge, mraw, fraw, vhe, vee);
  gemm_out<<<dim3(8, 64), 256, 0, stream>>>(xhi, xlo,
                                            wth + 3 * 262144, wtl + 3 * 262144,
                                            bo, (float*)d_out);
}